// Round 1
// baseline (334.343 us; speedup 1.0000x reference)
//
#include <hip/hip_runtime.h>
#include <hip/hip_bf16.h>

typedef __attribute__((ext_vector_type(8))) __bf16 bf16x8;
typedef __attribute__((ext_vector_type(4))) __bf16 bf16x4;
typedef __attribute__((ext_vector_type(4))) float f32x4;

constexpr int M  = 16384;
constexpr int K  = 512;   // both GEMM reduction dims (DIN = H = 512)
constexpr int BK = 32;
constexpr int R  = 64;    // rows per block

__device__ __forceinline__ void async_copy16(const void* gsrc, void* ldst) {
  __builtin_amdgcn_global_load_lds(
      (const __attribute__((address_space(1))) unsigned int*)(gsrc),
      (__attribute__((address_space(3))) unsigned int*)(ldst),
      16, 0, 0);
}

__device__ __forceinline__ float frcp(float x) { return __builtin_amdgcn_rcpf(x); }
__device__ __forceinline__ float ftanh(float x) {
  return 1.0f - 2.0f * frcp(1.0f + __expf(2.0f * x));
}
__device__ __forceinline__ float fsigm(float x) { return frcp(1.0f + __expf(-x)); }

// ---------------------------------------------------------------------------
// Fully fused LSTM-cell kernel. One block = 64 rows, 512 threads (8 waves,
// each wave owns a 64-col slice of N=512). Per net j in {i2,f2,z}:
//   layer1: h1 = hx(fp32->bf16 reg-staged) @ W1[j]^T  -> tanh -> a1 (LDS,
//           XOR-swizzled so layer2 A-frag ds_read_b128 is conflict-free)
//   layer2: h2 = a1 @ W2[j]^T   (A-operand straight from LDS, no staging)
//   j=0 -> i2 regs (bf16), j=1 -> f2 regs, j=2 -> z + combine:
//           out = f2*cx2 + i2*z   (fp32, direct)
// W tiles stream via global_load_lds (2-phase ping-pong: stage(k+1) issued
// right after barrier(k), drained at barrier(k+1)); W1b/W2b are a 3 MB
// broadcast -> L2-resident, so one MFMA phase of cover hides the latency.
// LDS: Wbuf 2x[512][32] (64KB) | Abuf 2x[64][32] (8KB) | a1 [64][512] (64KB)
//    = 136 KB -> 1 block/CU, grid 256 = exactly 1 block per CU.
// Numerics match the previous version bit-for-bit-ish: same bf16 rounding
// points (hx, a1, gates), same MFMA accumulation order, same fast-math act.
// NOTE: never runtime-index acc[]/i2s[]/f2s[] (scratch spill) - all loops
// over them are fully unrolled.
// ---------------------------------------------------------------------------
__global__ __launch_bounds__(512, 2) void fused_kernel(
    const float* __restrict__ hx,    // [M][512] fp32
    const __bf16* __restrict__ W1b,  // [3][512][512] bf16 (N,K) row-major
    const __bf16* __restrict__ W2b,  // [3][512][512] bf16
    const float* __restrict__ b1,    // [7][512] fp32 (use row 2j+1)
    const float* __restrict__ b2,    // [7][512] fp32
    const float* __restrict__ cx2,   // [M][512] fp32
    float* __restrict__ out)         // [M][512] fp32
{
  __shared__ __align__(16) __bf16 smem[69632];   // 136 KB
  __bf16* const a1 = smem + 36864;

  const int mbase = blockIdx.x * R;
  const int tid = threadIdx.x, wid = tid >> 6, lane = tid & 63;
  const int wn   = wid * 64;                       // wave's col slice
  const int srow = wid * 16 + (lane >> 2);         // gload_lds row mapping
  const int scol = ((lane & 3) ^ ((lane >> 3) & 3)) * 8;  // swizzled src chunk
  const int fr = lane & 15, kc = lane >> 4;
  const int sw = (fr >> 1) & 3, rowq = kc * 4;

  // A (hx) reg-staging mapping: thread -> (row, 4-float chunk); dest chunk is
  // pre-swizzled so frag reads use the same (kc^sw) un-swizzle as W tiles.
  const int ar = tid >> 3, ac = tid & 7;
  const int adst = ar * 32 + (((ac >> 1) ^ ((ar >> 1) & 3)) * 8) + (ac & 1) * 4;
  const float* hxrow = hx + (size_t)(mbase + ar) * K + ac * 4;

  bf16x4 i2s[4][4], f2s[4][4];   // gate stash across the j-loop

  auto stageW = [&](int p, int k0, const __bf16* Wj) {
#pragma unroll
    for (int r = 0; r < 4; ++r)
      async_copy16(Wj + (size_t)(r * 128 + srow) * K + (k0 + scol),
                   (void*)&smem[p * 16384 + (r * 128 + wid * 16) * BK]);
  };

#pragma unroll 1
  for (int j = 0; j < 3; ++j) {
    const __bf16* WL1 = W1b + (size_t)j * 262144;
    const __bf16* WL2 = W2b + (size_t)j * 262144;

    // ---------------- layer 1 ----------------
    {
      f32x4 acc[4][4] = {};
      {
        f32x4 av = *(const f32x4*)(hxrow);   // issue before stageW: oldest vmem
        stageW(0, 0, WL1);
        *(bf16x4*)&smem[32768 + adst] = __builtin_convertvector(av, bf16x4);
      }
      int p = 0;
      for (int k0 = 0; k0 < K; k0 += BK) {
        __syncthreads();               // drains stage(p) issued last iter
        const bool pre = k0 + BK < K;
        f32x4 av;
        if (pre) {
          av = *(const f32x4*)(hxrow + k0 + BK);  // oldest -> vmcnt leaves W in flight
          stageW(p ^ 1, k0 + BK, WL1);
        }
        bf16x8 af[4], bfr[4];
#pragma unroll
        for (int i = 0; i < 4; ++i) {
          af[i]  = *(const bf16x8*)&smem[32768 + p * 2048 +
                                         (i * 16 + fr) * BK + ((kc ^ sw) * 8)];
          bfr[i] = *(const bf16x8*)&smem[p * 16384 +
                                         (wn + i * 16 + fr) * BK + ((kc ^ sw) * 8)];
        }
#pragma unroll
        for (int mi = 0; mi < 4; ++mi)
#pragma unroll
          for (int ni = 0; ni < 4; ++ni)
            acc[mi][ni] = __builtin_amdgcn_mfma_f32_16x16x32_bf16(
                af[mi], bfr[ni], acc[mi][ni], 0, 0, 0);
        if (pre)   // next-iter A tile; published by next iteration's barrier
          *(bf16x4*)&smem[32768 + (p ^ 1) * 2048 + adst] =
              __builtin_convertvector(av, bf16x4);
        p ^= 1;
      }

      // epilogue: bias + tanh -> a1 (XOR swizzle on element index keeps
      // layer2's 16-lane/row ds_read_b128 at <=2-way banks; writes are b16,
      // <=2 lanes per bank word -> free per m136)
      const float* b1j = b1 + (2 * j + 1) * 512 + wn;
      float bv[4];
#pragma unroll
      for (int ni = 0; ni < 4; ++ni) bv[ni] = b1j[ni * 16 + fr];
#pragma unroll
      for (int mi = 0; mi < 4; ++mi)
#pragma unroll
        for (int ni = 0; ni < 4; ++ni)
#pragma unroll
          for (int r = 0; r < 4; ++r) {
            const int row = mi * 16 + rowq + r;       // C layout: row=rowq+r
            const int col = wn + ni * 16 + fr;        //           col=fr
            a1[(row * 512 + col) ^ ((row & 7) << 3)] =
                (__bf16)ftanh(acc[mi][ni][r] + bv[ni]);
          }
    }

    // ---------------- layer 2 ----------------
    {
      // safe pre-barrier: every wave past the last k-loop barrier implies all
      // Wbuf0 reads (k0=448 phase) are complete; a1 writes go to a disjoint
      // region and are published by the first loop barrier below.
      stageW(0, 0, WL2);
      f32x4 acc[4][4] = {};
      int p = 0;
      for (int k0 = 0; k0 < K; k0 += BK) {
        __syncthreads();
        if (k0 + BK < K) stageW(p ^ 1, k0 + BK, WL2);
        bf16x8 af[4], bfr[4];
#pragma unroll
        for (int i = 0; i < 4; ++i) {
          const int row = i * 16 + fr;
          af[i]  = *(const bf16x8*)&a1[(row * 512 + k0 + kc * 8) ^
                                       ((row & 7) << 3)];
          bfr[i] = *(const bf16x8*)&smem[p * 16384 +
                                         (wn + i * 16 + fr) * BK + ((kc ^ sw) * 8)];
        }
#pragma unroll
        for (int mi = 0; mi < 4; ++mi)
#pragma unroll
          for (int ni = 0; ni < 4; ++ni)
            acc[mi][ni] = __builtin_amdgcn_mfma_f32_16x16x32_bf16(
                af[mi], bfr[ni], acc[mi][ni], 0, 0, 0);
        p ^= 1;
      }

      const float* b2j = b2 + (2 * j + 1) * 512 + wn;
      float bv[4];
#pragma unroll
      for (int ni = 0; ni < 4; ++ni) bv[ni] = b2j[ni * 16 + fr];
      if (j == 0) {
#pragma unroll
        for (int mi = 0; mi < 4; ++mi)
#pragma unroll
          for (int ni = 0; ni < 4; ++ni)
#pragma unroll
            for (int r = 0; r < 4; ++r)
              i2s[mi][ni][r] = (__bf16)fsigm(ftanh(acc[mi][ni][r] + bv[ni]));
      } else if (j == 1) {
#pragma unroll
        for (int mi = 0; mi < 4; ++mi)
#pragma unroll
          for (int ni = 0; ni < 4; ++ni)
#pragma unroll
            for (int r = 0; r < 4; ++r)
              f2s[mi][ni][r] = (__bf16)fsigm(ftanh(acc[mi][ni][r] + bv[ni]));
      } else {
        // z net: z = tanh(sigmoid(tanh(.))), then cy2 = f2*cx2 + i2*z
#pragma unroll
        for (int mi = 0; mi < 4; ++mi)
#pragma unroll
          for (int ni = 0; ni < 4; ++ni)
#pragma unroll
            for (int r = 0; r < 4; ++r) {
              const __bf16 zb =
                  (__bf16)ftanh(fsigm(ftanh(acc[mi][ni][r] + bv[ni])));
              const size_t idx = (size_t)(mbase + mi * 16 + rowq + r) * 512 +
                                 (wn + ni * 16 + fr);
              out[idx] = (float)f2s[mi][ni][r] * cx2[idx] +
                         (float)i2s[mi][ni][r] * (float)zb;
            }
      }
    }
  }
}

// pick rows 2y+1 of W1/W2 ([7][512][512] fp32) -> [3][512][512] bf16 each
__global__ __launch_bounds__(256) void cvt_w6(const float* __restrict__ W1,
                                              const float* __restrict__ W2,
                                              __bf16* __restrict__ dst) {
  const int y = blockIdx.y;  // 0..2 -> W1 nets, 3..5 -> W2 nets
  const float* src = (y < 3) ? W1 + (size_t)(2 * y + 1) * 262144
                             : W2 + (size_t)(2 * (y - 3) + 1) * 262144;
  __bf16* d = dst + (size_t)y * 262144;
  const size_t i = ((size_t)blockIdx.x * 256 + threadIdx.x) * 4;
  f32x4 v = *(const f32x4*)&src[i];
  *(bf16x4*)&d[i] = __builtin_convertvector(v, bf16x4);
}

extern "C" void kernel_launch(void* const* d_in, const int* in_sizes, int n_in,
                              void* d_out, int out_size, void* d_ws, size_t ws_size,
                              hipStream_t stream) {
  const float* hx  = (const float*)d_in[0];
  // d_in[1] = cx1 (dead: cy1 is never returned)
  const float* cx2 = (const float*)d_in[2];
  const float* W1  = (const float*)d_in[3];
  const float* b1  = (const float*)d_in[4];
  const float* W2  = (const float*)d_in[5];
  const float* b2  = (const float*)d_in[6];

  // ws: W1b @0 (1.5 MB) | W2b @1572864 (1.5 MB)
  __bf16* W1b = (__bf16*)d_ws;
  __bf16* W2b = W1b + 3 * 262144;

  cvt_w6<<<dim3(256, 6), 256, 0, stream>>>(W1, W2, W1b);
  fused_kernel<<<256, 512, 0, stream>>>(hx, W1b, W2b, b1, b2, cx2,
                                        (float*)d_out);
}